// Round 5
// baseline (9493.401 us; speedup 1.0000x reference)
//
#include <hip/hip_runtime.h>
#include <hip/hip_bf16.h>

// Problem constants (match reference)
#define Tn 2048
#define Bn 32
#define Dn 256
#define Un 256
#define NBLK 8

using short8 = __attribute__((ext_vector_type(8))) short;
using f32x4  = __attribute__((ext_vector_type(4))) float;
using int4v  = __attribute__((ext_vector_type(4))) int;
using u16x2  = __attribute__((ext_vector_type(2))) unsigned short;

__device__ __forceinline__ unsigned short f2bf(float f) {
    unsigned int u = __builtin_bit_cast(unsigned int, f);
    u += 0x7fffu + ((u >> 16) & 1u);   // round-to-nearest-even
    return (unsigned short)(u >> 16);
}
__device__ __forceinline__ float bf2f(unsigned short v) {
    unsigned int u = ((unsigned int)v) << 16;
    return __builtin_bit_cast(float, u);
}
__device__ __forceinline__ float rcp_f(float x) { return __builtin_amdgcn_rcpf(x); }
__device__ __forceinline__ float sigm(float x)   { return rcp_f(1.0f + __expf(-x)); }
__device__ __forceinline__ float tanh_f(float x) { return 1.0f - 2.0f * rcp_f(__expf(2.0f * x) + 1.0f); }

// ---------------------------------------------------------------------------
// Kernel 1: zx = data @ Wx, stored bf16, layout [T][B][1024]. (Unchanged —
// proven rounds 1-3, ~250us. Not the bottleneck.)
// ---------------------------------------------------------------------------
__global__ __launch_bounds__(512) void gemm_zx(const float* __restrict__ data,
                                               const float* __restrict__ Wx,
                                               unsigned short* __restrict__ zws)
{
    __shared__ unsigned short BsubT[128 * 40];

    const int bid = blockIdx.x;
    const int bn = bid & 7;
    const int bm = bid >> 3;
    const int tid = threadIdx.x;
    const int lane = tid & 63, wid = tid >> 6;
    const int wm = wid >> 2, wn = wid & 3;
    const int l15 = lane & 15, lk = lane >> 4;

    f32x4 acc[4][2];
    #pragma unroll
    for (int mt = 0; mt < 4; ++mt)
        #pragma unroll
        for (int nt = 0; nt < 2; ++nt)
            acc[mt][nt] = f32x4{0.f, 0.f, 0.f, 0.f};

    const int colStage = tid & 127;
    const int kqStage  = tid >> 7;

    for (int ks = 0; ks < 8; ++ks) {
        __syncthreads();
        {
            const float* wp = Wx + (size_t)(ks * 32 + kqStage) * 1024 + bn * 128 + colStage;
            #pragma unroll
            for (int kk = 0; kk < 8; ++kk) {
                float v = wp[(size_t)kk * 4 * 1024];
                BsubT[colStage * 40 + (kqStage + kk * 4)] = f2bf(v);
            }
        }
        __syncthreads();

        short8 afr[4];
        #pragma unroll
        for (int mt = 0; mt < 4; ++mt) {
            int row = bm * 128 + wm * 64 + mt * 16 + l15;
            const float* ap = data + (size_t)row * 256 + ks * 32 + lk * 8;
            float4 a0 = *(const float4*)(ap);
            float4 a1 = *(const float4*)(ap + 4);
            short8 a;
            a[0] = (short)f2bf(a0.x); a[1] = (short)f2bf(a0.y);
            a[2] = (short)f2bf(a0.z); a[3] = (short)f2bf(a0.w);
            a[4] = (short)f2bf(a1.x); a[5] = (short)f2bf(a1.y);
            a[6] = (short)f2bf(a1.z); a[7] = (short)f2bf(a1.w);
            afr[mt] = a;
        }
        #pragma unroll
        for (int nt = 0; nt < 2; ++nt) {
            int colL = wn * 32 + nt * 16 + l15;
            short8 bfr = *(const short8*)&BsubT[colL * 40 + lk * 8];
            #pragma unroll
            for (int mt = 0; mt < 4; ++mt)
                acc[mt][nt] = __builtin_amdgcn_mfma_f32_16x16x32_bf16(afr[mt], bfr, acc[mt][nt], 0, 0, 0);
        }
    }

    #pragma unroll
    for (int mt = 0; mt < 4; ++mt) {
        #pragma unroll
        for (int nt = 0; nt < 2; ++nt) {
            int col = bn * 128 + wn * 32 + nt * 16 + l15;
            #pragma unroll
            for (int r = 0; r < 4; ++r) {
                int row = bm * 128 + wm * 64 + mt * 16 + lk * 4 + r;
                int b_ = row >> 11;
                int t_ = row & 2047;
                zws[(size_t)(t_ * 32 + b_) * 1024 + col] = f2bf(acc[mt][nt][r]);
            }
        }
    }
}

// ---------------------------------------------------------------------------
// Kernel 1b: WhT[col][k] = bf16(Wh[k][col]) — one-time transpose.
// ---------------------------------------------------------------------------
__global__ void wh_transpose(const float* __restrict__ Wh,
                             unsigned short* __restrict__ WhT)
{
    const int c = blockIdx.x;    // 0..1023 (gate column)
    const int k = threadIdx.x;   // 0..255
    WhT[c * 256 + k] = f2bf(Wh[(size_t)k * 1024 + c]);
}

// ---------------------------------------------------------------------------
// Kernel 2: recurrence via SELF-VALIDATING TAGGED exchange through the LLC.
// 8 blocks x 256 thr (4 waves = 2m x 2n). Block owns 32 u's; its 128 gate-
// cols of Wh live in registers. h(t) published as tagged dwords:
//   dword = ((t+1) << 16) | bf16(h)        (dword stores are atomic)
// Consumers retry-load their A-fragment (UC sc0 sc1) until the tag-sum over
// all 64 dwords equals 64*t mod 2^16 (uniqueness proof: possible tag mix
// {0, t-2, t} only sums to target when all fresh). No flags, no store-acks,
// no barriers — the poll IS the data load. zx prefetched 2 steps ahead and
// out-stores deferred one step, so they retire before any vmcnt(0).
// ---------------------------------------------------------------------------
struct ZxRegs { unsigned short v[4][4]; };   // [gate][r]

__global__ __launch_bounds__(256, 1) void lstm_rec(
    const unsigned short* __restrict__ WhT,   // [1024][256] bf16
    const float* __restrict__ bias,           // [1024]
    const unsigned short* __restrict__ zws,   // [T][32][1024] bf16
    unsigned int* __restrict__ hT,            // [2][32][256] tagged dwords (memset 0)
    float* __restrict__ out)                  // [32][T][256] f32
{
    const int chunk = blockIdx.x;             // 0..7
    const int tid  = threadIdx.x;
    const int lane = tid & 63;
    const int wid  = tid >> 6;                // 0..3
    const int wm   = wid >> 1;                // batch half (m)
    const int wn   = wid & 1;                 // u half (n)
    const int l15  = lane & 15, lk = lane >> 4;

    const int u = chunk * 32 + wn * 16 + l15; // this lane's unit

    // ---- Wh fragments into registers: Bf[g][ks], col = g*256+u (128 VGPR)
    short8 Bf[4][8];
    #pragma unroll
    for (int g = 0; g < 4; ++g)
        #pragma unroll
        for (int ks = 0; ks < 8; ++ks)
            Bf[g][ks] = *(const short8*)(WhT + (size_t)(g * 256 + u) * 256 + ks * 32 + lk * 8);

    float bias_r[4];
    #pragma unroll
    for (int g = 0; g < 4; ++g) bias_r[g] = bias[g * 256 + u];

    float c_state[4];
    #pragma unroll
    for (int r = 0; r < 4; ++r) c_state[r] = 0.0f;

    // zx double-buffer by t-parity: zxE for even t, zxO for odd t.
    ZxRegs zxE, zxO;
    #pragma unroll
    for (int g = 0; g < 4; ++g)
        #pragma unroll
        for (int r = 0; r < 4; ++r) {
            zxE.v[g][r] = zws[(size_t)(0 * 32 + wm * 16 + lk * 4 + r) * 1024 + g * 256 + u];
            zxO.v[g][r] = zws[(size_t)(1 * 32 + wm * 16 + lk * 4 + r) * 1024 + g * 256 + u];
        }

    float hprev[4];    // h(t-1) values, out-store deferred one step

    // ---- gate computation + tagged publish (shared by all steps)
    auto gates_publish = [&](int t, const ZxRegs& cur, const f32x4* acc) {
        unsigned int* hw = hT + (size_t)(t & 1) * (Bn * Un);
        #pragma unroll
        for (int r = 0; r < 4; ++r) {
            const float zi = acc[0][r] + bf2f(cur.v[0][r]) + bias_r[0];
            const float zf = acc[1][r] + bf2f(cur.v[1][r]) + bias_r[1];
            const float zg = acc[2][r] + bf2f(cur.v[2][r]) + bias_r[2];
            const float zo = acc[3][r] + bf2f(cur.v[3][r]) + bias_r[3];
            const float ig = sigm(zi), fg = sigm(zf);
            const float gg = tanh_f(zg), og = sigm(zo);
            const float cs = fg * c_state[r] + ig * gg;
            c_state[r] = cs;
            const float h = og * tanh_f(cs);

            const int b = wm * 16 + lk * 4 + r;
            unsigned long long haddr = (unsigned long long)(hw + (size_t)b * 256 + u);
            unsigned int dw = ((unsigned int)(t + 1) << 16) | (unsigned int)f2bf(h);
            asm volatile("global_store_dword %0, %1, off sc0 sc1"
                         :: "v"(haddr), "v"(dw) : "memory");   // fire-and-forget
            hprev[r] = h;
        }
    };

    // ---- step t >= 1
    auto step = [&](int t, ZxRegs& zxUse) {
        // retry-validate the tagged A-fragment of h(t-1)
        const unsigned int* hb = hT + (size_t)((t - 1) & 1) * (Bn * Un)
                                    + (size_t)(wm * 16 + l15) * 256;
        const unsigned short target = (unsigned short)(64u * (unsigned int)t);
        int4v tg[16];
        while (true) {
            #pragma unroll
            for (int ks = 0; ks < 8; ++ks) {
                unsigned long long a0 = (unsigned long long)(hb + ks * 32 + lk * 8);
                asm volatile("global_load_dwordx4 %0, %1, off sc0 sc1"
                             : "=v"(tg[2 * ks]) : "v"(a0) : "memory");
                asm volatile("global_load_dwordx4 %0, %1, off sc0 sc1"
                             : "=v"(tg[2 * ks + 1]) : "v"(a0 + 16) : "memory");
            }
            asm volatile("s_waitcnt vmcnt(0)" ::: "memory");
            __builtin_amdgcn_sched_barrier(0);   // rule #18: pin uses after waitcnt
            u16x2 s = {0, 0};
            #pragma unroll
            for (int i = 0; i < 16; ++i)
                #pragma unroll
                for (int j = 0; j < 4; ++j)
                    s += __builtin_bit_cast(u16x2, tg[i][j]);
            if (__all((int)(s[1] == target))) break;
        }
        __builtin_amdgcn_sched_barrier(0);

        // off-critical-path: deferred out-store of h(t-1), zx refill for t+2.
        // These retire during MFMA+gates+next-poll (~1800cy) before any vmcnt(0).
        #pragma unroll
        for (int r = 0; r < 4; ++r) {
            const int b = wm * 16 + lk * 4 + r;
            out[(size_t)b * (Tn * Un) + (size_t)(t - 1) * Un + u] = hprev[r];
        }
        ZxRegs cur = zxUse;   // capture before refill
        if (t + 2 < Tn) {
            #pragma unroll
            for (int g = 0; g < 4; ++g)
                #pragma unroll
                for (int r = 0; r < 4; ++r)
                    zxUse.v[g][r] = zws[((size_t)(t + 2) * 32 + wm * 16 + lk * 4 + r) * 1024
                                        + g * 256 + u];
        }

        // repack (strip tags) + 32 MFMA (4 independent 8-chains)
        f32x4 acc[4];
        #pragma unroll
        for (int g = 0; g < 4; ++g) acc[g] = f32x4{0.f, 0.f, 0.f, 0.f};
        #pragma unroll
        for (int ks = 0; ks < 8; ++ks) {
            int4v p;
            p[0] = (int)((((unsigned)tg[2 * ks][1]) << 16)     | ((unsigned)tg[2 * ks][0]     & 0xffffu));
            p[1] = (int)((((unsigned)tg[2 * ks][3]) << 16)     | ((unsigned)tg[2 * ks][2]     & 0xffffu));
            p[2] = (int)((((unsigned)tg[2 * ks + 1][1]) << 16) | ((unsigned)tg[2 * ks + 1][0] & 0xffffu));
            p[3] = (int)((((unsigned)tg[2 * ks + 1][3]) << 16) | ((unsigned)tg[2 * ks + 1][2] & 0xffffu));
            short8 af = __builtin_bit_cast(short8, p);
            #pragma unroll
            for (int g = 0; g < 4; ++g)
                acc[g] = __builtin_amdgcn_mfma_f32_16x16x32_bf16(af, Bf[g][ks], acc[g], 0, 0, 0);
        }

        gates_publish(t, cur, acc);
    };

    // ---- t = 0: acc = 0 (h(-1)=0), publish h(0), refill zxE with zx(2)
    {
        f32x4 acc0[4];
        #pragma unroll
        for (int g = 0; g < 4; ++g) acc0[g] = f32x4{0.f, 0.f, 0.f, 0.f};
        ZxRegs cur = zxE;
        #pragma unroll
        for (int g = 0; g < 4; ++g)
            #pragma unroll
            for (int r = 0; r < 4; ++r)
                zxE.v[g][r] = zws[((size_t)2 * 32 + wm * 16 + lk * 4 + r) * 1024 + g * 256 + u];
        gates_publish(0, cur, acc0);
    }

    // ---- main loop: pairs (odd, even); Tn even so last pair is (2045,2046),
    // then the single tail step 2047 (odd).
    for (int t = 1; t + 1 < Tn; t += 2) {
        step(t,     zxO);
        step(t + 1, zxE);
    }
    step(Tn - 1, zxO);

    // final out-store of h(Tn-1)
    #pragma unroll
    for (int r = 0; r < 4; ++r) {
        const int b = wm * 16 + lk * 4 + r;
        out[(size_t)b * (Tn * Un) + (size_t)(Tn - 1) * Un + u] = hprev[r];
    }
}

// ---------------------------------------------------------------------------
extern "C" void kernel_launch(void* const* d_in, const int* in_sizes, int n_in,
                              void* d_out, int out_size, void* d_ws, size_t ws_size,
                              hipStream_t stream)
{
    const float* data = (const float*)d_in[0];   // [32,2048,256]
    const float* Wx   = (const float*)d_in[1];   // [256,1024]
    const float* Wh   = (const float*)d_in[2];   // [256,1024]
    const float* bias = (const float*)d_in[3];   // [1024]
    float* out = (float*)d_out;

    char* ws = (char*)d_ws;
    unsigned short* zws = (unsigned short*)ws;                 // 128 MB: [T][B][1024] bf16
    size_t off = (size_t)Tn * Bn * 1024 * 2;
    unsigned short* WhT = (unsigned short*)(ws + off);         // 512 KB
    off += (size_t)1024 * 256 * 2;
    unsigned int* hT = (unsigned int*)(ws + off);              // 64 KB: [2][32][256] tagged

    // tags must start at 0 (uniqueness proof depends on it) — every launch.
    hipMemsetAsync(hT, 0, (size_t)2 * Bn * Un * sizeof(unsigned int), stream);

    wh_transpose<<<dim3(1024), dim3(256), 0, stream>>>(Wh, WhT);
    gemm_zx<<<dim3(4096), dim3(512), 0, stream>>>(data, Wx, zws);
    lstm_rec<<<dim3(NBLK), dim3(256), 0, stream>>>(WhT, bias, zws, hT, out);
}